// Round 23
// baseline (599.874 us; speedup 1.0000x reference)
//
#include <hip/hip_runtime.h>
#include <math.h>

#define NB_IN   128
#define NBINS   39
#define NLM     400
#define NZO     512
#define NPAIR   780
#define NPACK   5530
#define TWOB    40
#define PI_D    3.14159265358979323846
#define SCALING 0.008164965809277261

// lbase(l) = sum_{l'<l} (2l'+1)(l'+1);  lbase(20) = 5530
__host__ __device__ __forceinline__ int lbase(int l){
  return l*(l-1)*(2*l-1)/3 + 3*l*(l-1)/2 + l;
}

__device__ __forceinline__ int lidx(int lm){
  int l = (int)sqrtf((float)lm);
  while ((l+1)*(l+1) <= lm) ++l;
  while (l*l > lm) --l;
  return l;
}

// Wigner little-d via Jacobi sum (one-shot)
__device__ double wigner_d(int l, int m, int n, double beta, const double* lg){
  double cb = cos(0.5*beta), sb = sin(0.5*beta);
  double lcb = log(cb), lsb = log(sb);
  double pref = 0.5*(lg[l+m]+lg[l-m]+lg[l+n]+lg[l-n]);
  int s0 = 0 > (n-m) ? 0 : (n-m);
  int s1 = (l+n) < (l-m) ? (l+n) : (l-m);
  double val = 0.0;
  for (int s = s0; s <= s1; ++s){
    double c = pref - (lg[l+n-s]+lg[s]+lg[m-n+s]+lg[l-m-s]);
    double t = exp(c + (double)(2*l+n-m-2*s)*lcb + (double)(m-n+2*s)*lsb);
    val += ((m-n+s)&1) ? -t : t;
  }
  return val;
}

// fast Wigner: 2 log + 1 exp + ratio recurrence over s (fp64)
__device__ double wigner_fast(int l, int m, int n, double beta, const double* lg){
  double cb = cos(0.5*beta), sb = sin(0.5*beta);
  double lcb = log(cb), lsb = log(sb);
  double pref = 0.5*(lg[l+m]+lg[l-m]+lg[l+n]+lg[l-n]);
  int s0 = 0 > (n-m) ? 0 : (n-m);
  int s1 = (l+n) < (l-m) ? (l+n) : (l-m);
  double ratio = (sb*sb)/(cb*cb);
  double t = exp(pref - (lg[l+n-s0]+lg[s0]+lg[m-n+s0]+lg[l-m-s0])
               + (double)(2*l+n-m-2*s0)*lcb + (double)(m-n+2*s0)*lsb);
  double sgn = ((m-n+s0)&1) ? -1.0 : 1.0;
  double acc = 0.0;
  for (int s = s0; s <= s1; ++s){
    acc += sgn*t;
    sgn = -sgn;
    t *= ratio * ((double)((l+n-s)*(l-m-s)) / (double)((s+1)*(m-n+s+1)));
  }
  return acc;
}

// ---- constants: k_init (lg, wq, psort, ipsort, ridx2, wsyn) ----------
__global__ void k_init(double* lg, double* wq, int* psort, int* ipsort,
                       int* ridx2, float2* wsyn){
  int t = threadIdx.x;  // 256
  if (t == 0){
    lg[0] = 0.0; double acc = 0.0;
    for (int k = 1; k <= 40; ++k){ acc += log((double)k); lg[k] = acc; }
  }
  for (int p = t; p < NPAIR; p += 256){
    int mj = p/39, njs = p%39, d = njs-19, ad = d<0?-d:d;
    int lam = mj > ad ? mj : ad;
    int pre = (lam==0) ? 0 : (2*lam-1)*lam;
    int rank = (mj < lam) ? (2*mj + ((njs==19+lam)?1:0))
                          : (2*lam + (njs-(19-lam)));
    int R = pre + rank;                   // global sorted rank
    psort[R] = mj | (njs<<8);
    ipsort[p] = R;                        // natural (mj*39+njs) -> sorted
    int info = mj | (njs<<8);
    for (int l = lam; l < 20; ++l)
      ridx2[lbase(l) + R] = info | (l<<16);
  }
  if (t < 128){
    double theta = PI_D*(2*t+1)/256.0;
    double s = 0.0;
    for (int k = 0; k < 64; ++k) s += sin((2*k+1)*theta)/(double)(2*k+1);
    wq[t] = (2.0/64.0)*sin(theta)*s;
  }
  // wsyn[njs*40+g] = e^{i (njs-19) g 2pi/40}; Wm[mj][a] = wsyn[(19+mj)*40+a]
  for (int idx = t; idx < 1560; idx += 256){
    int njs = idx/40, g = idx%40;
    double ang = 2.0*PI_D*(double)(njs-19)*(double)g/40.0;
    wsyn[idx] = make_float2((float)cos(ang), (float)sin(ang));
  }
}

// ---- fused tables: [0,200) ws2 | [200,633) dinv3 sorted layout | [633,671) Fc
__global__ void k_tables(float* w_s2, float* dinv3, float2* Fc,
                         const int* ridx2, const double* lg, const double* wq){
  int bid = blockIdx.x, t = threadIdx.x;
  if (bid < 200){
    int tid = bid*256 + t;            // one eval per thread
    if (tid >= 128*NLM) return;
    int b = tid / NLM, lm = tid % NLM;
    int l = lidx(lm); int m = lm - l*l - l;
    double beta = PI_D*(2*b+1)/256.0;
    w_s2[b*NLM + lm] = (float)(wigner_fast(l, m, 0, beta, lg) * wq[b]);
  } else if (bid < 633){
    int idx = (bid-200)*256 + t;      // one eval per thread; b in [0,20)
    if (idx >= 20*NPACK) return;
    int b = idx / NPACK, k = idx % NPACK;
    int info = ridx2[k];
    int mj = info & 255, njs = (info>>8)&255, l = info>>16;
    int n = njs - 19, ad = n < 0 ? -n : n;
    int lam = mj > ad ? mj : ad;
    int pre = (lam==0) ? 0 : (2*lam-1)*lam;
    int rank_m = (mj < lam) ? (2*mj + ((njs == 19-lam) ? 1 : 0))
                            : (2*lam + (19 + lam - njs));
    float sgn = ((l+mj)&1) ? -1.f : 1.f;
    double beta = PI_D*(2*b+1)/80.0;
    float v = (float)((double)(2*l+1) * wigner_fast(l, mj, n, beta, lg));
    dinv3[b*NPACK + k] = v;
    dinv3[(39-b)*NPACK + lbase(l) + pre + rank_m] = sgn * v;  // d(pi-b) identity
  } else {
    int tid = (bid-633)*256 + t;
    if (tid >= 24*NLM) return;
    int p = tid / NLM, lm = tid % NLM;
    int l = lidx(lm); int m = lm - l*l - l;
    double beta = PI_D*(double)(p/8 + 1)/24.0;
    double alpha = (double)(p%8)*(PI_D/4.0);
    double d = wigner_d(l, m, 0, beta, lg);
    double a = (double)m*alpha;            // conj(F_k)
    Fc[tid] = make_float2((float)(d*cos(a)), (float)(d*sin(a)));
  }
}

__global__ void k_yc(const float* ker, const float2* Fc, float2* ycT){
  int tid = blockIdx.x*256 + threadIdx.x;
  if (tid >= NLM*NZO) return;
  int lm = tid / 512, io = tid % 512;
  int i = io >> 5, o = io & 31;
  float2 acc = make_float2(0.f, 0.f);
  for (int p = 0; p < 24; ++p){
    float kv = ker[io*24 + p];
    float2 f = Fc[p*NLM + lm];
    acc.x += kv*f.x; acc.y += kv*f.y;
  }
  acc.x *= (float)SCALING; acc.y *= (float)SCALING;
  ycT[((size_t)(o*16 + i))*NLM + lm] = acc;
}

// ---- pipeline --------------------------------------------------------
// xf[mj][b][zi]; 4-way ILP phase recurrence
__global__ __launch_bounds__(256) void k_dft(const float* x, float2* xf){
  __shared__ float rows[4][128];
  int t = threadIdx.x, g = t >> 6, lane = t & 63;
  int r = blockIdx.x*4 + g;
  int zi = r & 255, b = r >> 8;
  const float* xr = x + ((size_t)zi*128 + b)*128;
  rows[g][lane]    = xr[lane];
  rows[g][lane+64] = xr[lane+64];
  __syncthreads();
  if (lane < NBINS){
    int m = lane - 19;
    float th = -2.0f*(float)PI_D*(float)m/128.0f;
    float sn1, cs1; sincosf(th, &sn1, &cs1);
    float cs2 = cs1*cs1 - sn1*sn1, sn2 = 2.f*cs1*sn1;
    float cs4 = cs2*cs2 - sn2*sn2, sn4 = 2.f*cs2*sn2;
    float w0r = 1.f, w0i = 0.f;
    float w1r = cs1, w1i = sn1;
    float w2r = cs2, w2i = sn2;
    float w3r = cs1*cs2 - sn1*sn2, w3i = cs1*sn2 + sn1*cs2;
    float2 a0 = make_float2(0.f,0.f), a1 = a0, a2 = a0, a3 = a0;
    const float* rw = rows[g];
    #pragma unroll 4
    for (int q = 0; q < 32; ++q){
      float v0 = rw[4*q], v1 = rw[4*q+1], v2 = rw[4*q+2], v3 = rw[4*q+3];
      a0.x += v0*w0r; a0.y += v0*w0i;
      a1.x += v1*w1r; a1.y += v1*w1i;
      a2.x += v2*w2r; a2.y += v2*w2i;
      a3.x += v3*w3r; a3.y += v3*w3i;
      float nr;
      nr = w0r*cs4 - w0i*sn4; w0i = w0r*sn4 + w0i*cs4; w0r = nr;
      nr = w1r*cs4 - w1i*sn4; w1i = w1r*sn4 + w1i*cs4; w1r = nr;
      nr = w2r*cs4 - w2i*sn4; w2i = w2r*sn4 + w2i*cs4; w2r = nr;
      nr = w3r*cs4 - w3i*sn4; w3i = w3r*sn4 + w3i*cs4; w3r = nr;
    }
    float2 acc = make_float2(a0.x+a1.x+a2.x+a3.x, a0.y+a1.y+a2.y+a3.y);
    xf[((size_t)lane*128 + b)*256 + zi] = acc;
  }
}

// partial beta-contraction: xlp[c][lm][zi], c = 32-b chunk
__global__ void k_xlp(const float2* xf, const float* w_s2, float2* xlp){
  int lm = blockIdx.x, c = blockIdx.y, zi = threadIdx.x;
  int l = lidx(lm); int m = lm - l*l - l;
  int bin = m + 19;
  float2 acc = make_float2(0.f, 0.f);
  for (int b = c*32; b < c*32+32; ++b){
    float w = w_s2[b*NLM + lm];
    float2 v = xf[((size_t)bin*128 + b)*256 + zi];
    acc.x += w*v.x; acc.y += w*v.y;
  }
  xlp[((size_t)(c*NLM + lm))*256 + zi] = acc;
}

// sum chunks -> xlT[zi][lm]
__global__ void k_xlsum(const float2* xlp, float2* xlT){
  int lm = blockIdx.x, zi = threadIdx.x;
  float2 s = make_float2(0.f, 0.f);
  for (int c = 0; c < 4; ++c){
    float2 v = xlp[((size_t)(c*NLM + lm))*256 + zi];
    s.x += v.x; s.y += v.y;
  }
  xlT[(size_t)zi*NLM + lm] = s;
}

// zl2 in SORTED layout: z3[zo][k'], k' = lbase(l) + global pair rank
__global__ void k_zl2s(const float2* xlT, const float2* ycT, const int* ridx2,
                       float2* z3){
  int tid = blockIdx.x*256 + threadIdx.x;
  if (tid >= NZO*NPACK) return;
  int zo = tid / NPACK, k = tid % NPACK;
  int info = ridx2[k];
  int mj = info & 255, njs = (info>>8)&255, l = info>>16;
  int z = zo >> 5, o = zo & 31;
  int lmm = l*l + l + mj;
  int lmn = l*l + l + (njs - 19);
  const float2* xrow = xlT + (size_t)(z*16)*NLM;
  const float2* yrow = ycT + (size_t)(o*16)*NLM;
  float2 acc = make_float2(0.f, 0.f);
  #pragma unroll 16
  for (int i = 0; i < 16; ++i){
    float2 a  = xrow[i*NLM + lmm];
    float2 bb = yrow[i*NLM + lmn];
    acc.x += a.x*bb.x - a.y*bb.y;
    acc.y += a.x*bb.y + a.y*bb.x;
  }
  z3[tid] = acc;
}

// ---- stage 1 with z-register reuse: one thread per (zo,s), loop b ----
__global__ __launch_bounds__(256) void k_s1g(const float* dinv3, const float2* z3,
                                             const int* psort, float2* Cg){
  int tid = blockIdx.x*256 + threadIdx.x;
  if (tid >= NZO*NPAIR) return;
  int zo = tid / NPAIR, s = tid % NPAIR;
  int pk = psort[s];
  int mj = pk & 255, njs = (pk>>8)&255;
  int d_ = njs - 19, ad = d_ < 0 ? -d_ : d_;
  int lam = mj > ad ? mj : ad;
  const float2* zrow = z3 + (size_t)zo*NPACK;
  float2 zr[20];
  #pragma unroll
  for (int l = 0; l < 20; ++l){
    float2 v = zrow[lbase(l) + s];
    bool act = (l >= lam);
    zr[l].x = act ? v.x : 0.f;
    zr[l].y = act ? v.y : 0.f;
  }
  for (int b = 0; b < 40; ++b){
    const float* drow = dinv3 + (size_t)b*NPACK;
    float2 c = make_float2(0.f, 0.f);
    #pragma unroll
    for (int l = 0; l < 20; ++l){
      float dv = drow[lbase(l) + s];
      c.x += dv*zr[l].x;
      c.y += dv*zr[l].y;
    }
    Cg[((size_t)(zo*40 + b))*NPAIR + s] = c;   // coalesced, sorted order
  }
}

// ---- stage 2 flat: thread = (zob, mj, g0<10); radix-4 in registers ---
__global__ __launch_bounds__(256) void k_g(const float2* Cg, const int* ipsort,
                                           const float2* wsyn, float2* G){
  int tid = blockIdx.x*256 + threadIdx.x;
  if (tid >= NZO*40*200) return;
  int item = tid % 200, zob = tid / 200;
  int mj = item / 10, g0 = item % 10;
  const float2* crow = Cg + (size_t)zob*NPAIR;
  const int* ip = ipsort + mj*39;
  float2 S0 = make_float2(0.f,0.f), S1 = S0, S2 = S0, S3 = S0;
  for (int j = 0; j < 9; ++j){        // r=0: njs = 3+4j
    int njs = 3+4*j;
    float2 c = crow[ip[njs]]; float2 w = wsyn[njs*40 + g0];
    S0.x += c.x*w.x - c.y*w.y; S0.y += c.x*w.y + c.y*w.x;
  }
  for (int j = 0; j < 10; ++j){       // r=1: njs = 4j
    int njs = 4*j;
    float2 c = crow[ip[njs]]; float2 w = wsyn[njs*40 + g0];
    S1.x += c.x*w.x - c.y*w.y; S1.y += c.x*w.y + c.y*w.x;
  }
  for (int j = 0; j < 10; ++j){       // r=2: njs = 1+4j
    int njs = 1+4*j;
    float2 c = crow[ip[njs]]; float2 w = wsyn[njs*40 + g0];
    S2.x += c.x*w.x - c.y*w.y; S2.y += c.x*w.y + c.y*w.x;
  }
  for (int j = 0; j < 10; ++j){       // r=3: njs = 2+4j
    int njs = 2+4*j;
    float2 c = crow[ip[njs]]; float2 w = wsyn[njs*40 + g0];
    S3.x += c.x*w.x - c.y*w.y; S3.y += c.x*w.y + c.y*w.x;
  }
  float2* gb = G + (size_t)zob*800 + mj*40 + g0;
  gb[ 0] = make_float2(S0.x+S1.x+S2.x+S3.x, S0.y+S1.y+S2.y+S3.y);
  gb[10] = make_float2(S0.x-S1.y-S2.x+S3.y, S0.y+S1.x-S2.y-S3.x);
  gb[20] = make_float2(S0.x-S1.x+S2.x-S3.x, S0.y-S1.y+S2.y-S3.y);
  gb[30] = make_float2(S0.x+S1.y-S2.x-S3.y, S0.y-S1.x-S2.y+S3.x);
}

// ---- stage 3 flat: thread = (zob, a0<10, g); radix-4 in registers ----
__global__ __launch_bounds__(256) void k_o(const float2* G, const float2* wsyn,
                                           const float* bias, float* out){
  int tid = blockIdx.x*256 + threadIdx.x;
  if (tid >= NZO*40*400) return;
  int item = tid % 400, zob = tid / 400;
  int a0 = item / 40, g = item % 40;
  int o = (zob / 40) & 31;
  const float2* gb = G + (size_t)zob*800;
  float S0x = 0.f, S2x = 0.f;
  float2 S1 = make_float2(0.f,0.f), S3 = S1;
  for (int j = 0; j < 4; ++j){        // r=0: mj = 4+4j
    int mj = 4+4*j;
    float2 gv = gb[mj*40 + g]; float2 w = wsyn[(19+mj)*40 + a0];
    S0x += gv.x*w.x - gv.y*w.y;
  }
  for (int j = 0; j < 5; ++j){        // r=1: mj = 1+4j
    int mj = 1+4*j;
    float2 gv = gb[mj*40 + g]; float2 w = wsyn[(19+mj)*40 + a0];
    S1.x += gv.x*w.x - gv.y*w.y; S1.y += gv.x*w.y + gv.y*w.x;
  }
  for (int j = 0; j < 5; ++j){        // r=2: mj = 2+4j
    int mj = 2+4*j;
    float2 gv = gb[mj*40 + g]; float2 w = wsyn[(19+mj)*40 + a0];
    S2x += gv.x*w.x - gv.y*w.y;
  }
  for (int j = 0; j < 5; ++j){        // r=3: mj = 3+4j
    int mj = 3+4*j;
    float2 gv = gb[mj*40 + g]; float2 w = wsyn[(19+mj)*40 + a0];
    S3.x += gv.x*w.x - gv.y*w.y; S3.y += gv.x*w.y + gv.y*w.x;
  }
  float g0v = gb[g].x;
  float bv = bias[o];
  float* orow = out + (size_t)zob*1600;
  orow[(a0     )*40 + g] = g0v + 2.f*(S0x + S1.x + S2x + S3.x) + bv;
  orow[(a0 + 10)*40 + g] = g0v + 2.f*(S0x - S1.y - S2x + S3.y) + bv;
  orow[(a0 + 20)*40 + g] = g0v + 2.f*(S0x - S1.x + S2x - S3.x) + bv;
  orow[(a0 + 30)*40 + g] = g0v + 2.f*(S0x + S1.y - S2x - S3.y) + bv;
}

extern "C" void kernel_launch(void* const* d_in, const int* in_sizes, int n_in,
                              void* d_out, int out_size, void* d_ws, size_t ws_size,
                              hipStream_t stream) {
  const float* x    = (const float*)d_in[0];
  const float* ker  = (const float*)d_in[1];
  const float* bias = (const float*)d_in[2];
  float* out = (float*)d_out;

  char* ws = (char*)d_ws;
  size_t cur = 0;
  auto alloc = [&](size_t bytes)->char*{
    char* p = ws + cur;
    cur += (bytes + 255) & ~(size_t)255;
    return p;
  };
  double* lg     = (double*)alloc(64*8);
  double* wq     = (double*)alloc(128*8);
  int*    psort  = (int*)   alloc(NPAIR*4);
  int*    ipsort = (int*)   alloc(NPAIR*4);
  int*    ridx2  = (int*)   alloc(NPACK*4);
  float2* wsyn   = (float2*)alloc((size_t)1560*8);
  float*  w_s2   = (float*) alloc((size_t)NB_IN*NLM*4);
  float*  dinv3  = (float*) alloc((size_t)TWOB*NPACK*4);
  float2* Fc     = (float2*)alloc((size_t)24*NLM*8);
  float2* ycT    = (float2*)alloc((size_t)512*400*8);
  float2* xf     = (float2*)alloc((size_t)NBINS*128*256*8);
  float2* xlp    = (float2*)alloc((size_t)4*NLM*256*8);
  float2* xlT    = (float2*)alloc((size_t)256*NLM*8);
  float2* z3     = (float2*)alloc((size_t)NZO*NPACK*8);      // 45 MB
  float2* Cg     = (float2*)alloc((size_t)NZO*40*NPAIR*8);   // 128 MB
  float2* G      = (float2*)alloc((size_t)NZO*40*800*8);     // 131 MB
  (void)ws_size; (void)in_sizes; (void)n_in; (void)out_size;

  k_init  <<<1, 256, 0, stream>>>(lg, wq, psort, ipsort, ridx2, wsyn);
  k_tables<<<671, 256, 0, stream>>>(w_s2, dinv3, Fc, ridx2, lg, wq);
  k_yc    <<<800, 256, 0, stream>>>(ker, Fc, ycT);

  k_dft  <<<(256*128)/4, 256, 0, stream>>>(x, xf);
  k_xlp  <<<dim3(NLM, 4), 256, 0, stream>>>(xf, w_s2, xlp);
  k_xlsum<<<NLM, 256, 0, stream>>>(xlp, xlT);
  k_zl2s <<<(NZO*NPACK + 255)/256, 256, 0, stream>>>(xlT, ycT, ridx2, z3);
  k_s1g  <<<(NZO*NPAIR + 255)/256, 256, 0, stream>>>(dinv3, z3, psort, Cg);
  k_g    <<<(NZO*40*200 + 255)/256, 256, 0, stream>>>(Cg, ipsort, wsyn, G);
  k_o    <<<(NZO*40*400 + 255)/256, 256, 0, stream>>>(G, wsyn, bias, out);
}

// Round 24
// 396.507 us; speedup vs baseline: 1.5129x; 1.5129x over previous
//
#include <hip/hip_runtime.h>
#include <math.h>

#define NB_IN   128
#define NBINS   39
#define NLM     400
#define NZO     512
#define NPAIR   780
#define NPACK   5530
#define TWOB    40
#define PI_D    3.14159265358979323846
#define SCALING 0.008164965809277261

// lbase(l) = sum_{l'<l} (2l'+1)(l'+1);  lbase(20) = 5530
__host__ __device__ __forceinline__ int lbase(int l){
  return l*(l-1)*(2*l-1)/3 + 3*l*(l-1)/2 + l;
}

__device__ __forceinline__ int lidx(int lm){
  int l = (int)sqrtf((float)lm);
  while ((l+1)*(l+1) <= lm) ++l;
  while (l*l > lm) --l;
  return l;
}

// Wigner little-d via Jacobi sum (one-shot)
__device__ double wigner_d(int l, int m, int n, double beta, const double* lg){
  double cb = cos(0.5*beta), sb = sin(0.5*beta);
  double lcb = log(cb), lsb = log(sb);
  double pref = 0.5*(lg[l+m]+lg[l-m]+lg[l+n]+lg[l-n]);
  int s0 = 0 > (n-m) ? 0 : (n-m);
  int s1 = (l+n) < (l-m) ? (l+n) : (l-m);
  double val = 0.0;
  for (int s = s0; s <= s1; ++s){
    double c = pref - (lg[l+n-s]+lg[s]+lg[m-n+s]+lg[l-m-s]);
    double t = exp(c + (double)(2*l+n-m-2*s)*lcb + (double)(m-n+2*s)*lsb);
    val += ((m-n+s)&1) ? -t : t;
  }
  return val;
}

// fast Wigner: 2 log + 1 exp + ratio recurrence over s (fp64)
__device__ double wigner_fast(int l, int m, int n, double beta, const double* lg){
  double cb = cos(0.5*beta), sb = sin(0.5*beta);
  double lcb = log(cb), lsb = log(sb);
  double pref = 0.5*(lg[l+m]+lg[l-m]+lg[l+n]+lg[l-n]);
  int s0 = 0 > (n-m) ? 0 : (n-m);
  int s1 = (l+n) < (l-m) ? (l+n) : (l-m);
  double ratio = (sb*sb)/(cb*cb);
  double t = exp(pref - (lg[l+n-s0]+lg[s0]+lg[m-n+s0]+lg[l-m-s0])
               + (double)(2*l+n-m-2*s0)*lcb + (double)(m-n+2*s0)*lsb);
  double sgn = ((m-n+s0)&1) ? -1.0 : 1.0;
  double acc = 0.0;
  for (int s = s0; s <= s1; ++s){
    acc += sgn*t;
    sgn = -sgn;
    t *= ratio * ((double)((l+n-s)*(l-m-s)) / (double)((s+1)*(m-n+s+1)));
  }
  return acc;
}

// ---- constants: k_init (lg, wq, psort, ridx2, wsyn) ------------------
__global__ void k_init(double* lg, double* wq, int* psort, int* ridx2, float2* wsyn){
  int t = threadIdx.x;  // 256
  if (t == 0){
    lg[0] = 0.0; double acc = 0.0;
    for (int k = 1; k <= 40; ++k){ acc += log((double)k); lg[k] = acc; }
  }
  for (int p = t; p < NPAIR; p += 256){
    int mj = p/39, njs = p%39, d = njs-19, ad = d<0?-d:d;
    int lam = mj > ad ? mj : ad;
    int pre = (lam==0) ? 0 : (2*lam-1)*lam;
    int rank = (mj < lam) ? (2*mj + ((njs==19+lam)?1:0))
                          : (2*lam + (njs-(19-lam)));
    int R = pre + rank;                   // global sorted rank
    psort[R] = mj | (njs<<8);
    int info = mj | (njs<<8);
    for (int l = lam; l < 20; ++l)
      ridx2[lbase(l) + R] = info | (l<<16);
  }
  if (t < 128){
    double theta = PI_D*(2*t+1)/256.0;
    double s = 0.0;
    for (int k = 0; k < 64; ++k) s += sin((2*k+1)*theta)/(double)(2*k+1);
    wq[t] = (2.0/64.0)*sin(theta)*s;
  }
  // wsyn[njs*40+g] = e^{i (njs-19) g 2pi/40}; Wm[mj][a] = wsyn[(19+mj)*40+a]
  for (int idx = t; idx < 1560; idx += 256){
    int njs = idx/40, g = idx%40;
    double ang = 2.0*PI_D*(double)(njs-19)*(double)g/40.0;
    wsyn[idx] = make_float2((float)cos(ang), (float)sin(ang));
  }
}

// ---- fused tables: [0,200) ws2 | [200,633) dinv3 sorted layout | [633,671) Fc
__global__ void k_tables(float* w_s2, float* dinv3, float2* Fc,
                         const int* ridx2, const double* lg, const double* wq){
  int bid = blockIdx.x, t = threadIdx.x;
  if (bid < 200){
    int tid = bid*256 + t;            // one eval per thread
    if (tid >= 128*NLM) return;
    int b = tid / NLM, lm = tid % NLM;
    int l = lidx(lm); int m = lm - l*l - l;
    double beta = PI_D*(2*b+1)/256.0;
    w_s2[b*NLM + lm] = (float)(wigner_fast(l, m, 0, beta, lg) * wq[b]);
  } else if (bid < 633){
    int idx = (bid-200)*256 + t;      // one eval per thread; b in [0,20)
    if (idx >= 20*NPACK) return;
    int b = idx / NPACK, k = idx % NPACK;
    int info = ridx2[k];
    int mj = info & 255, njs = (info>>8)&255, l = info>>16;
    int n = njs - 19, ad = n < 0 ? -n : n;
    int lam = mj > ad ? mj : ad;
    int pre = (lam==0) ? 0 : (2*lam-1)*lam;
    int rank_m = (mj < lam) ? (2*mj + ((njs == 19-lam) ? 1 : 0))
                            : (2*lam + (19 + lam - njs));
    float sgn = ((l+mj)&1) ? -1.f : 1.f;
    double beta = PI_D*(2*b+1)/80.0;
    float v = (float)((double)(2*l+1) * wigner_fast(l, mj, n, beta, lg));
    dinv3[b*NPACK + k] = v;
    dinv3[(39-b)*NPACK + lbase(l) + pre + rank_m] = sgn * v;  // d(pi-b) identity
  } else {
    int tid = (bid-633)*256 + t;
    if (tid >= 24*NLM) return;
    int p = tid / NLM, lm = tid % NLM;
    int l = lidx(lm); int m = lm - l*l - l;
    double beta = PI_D*(double)(p/8 + 1)/24.0;
    double alpha = (double)(p%8)*(PI_D/4.0);
    double d = wigner_d(l, m, 0, beta, lg);
    double a = (double)m*alpha;            // conj(F_k)
    Fc[tid] = make_float2((float)(d*cos(a)), (float)(d*sin(a)));
  }
}

__global__ void k_yc(const float* ker, const float2* Fc, float2* ycT){
  int tid = blockIdx.x*256 + threadIdx.x;
  if (tid >= NLM*NZO) return;
  int lm = tid / 512, io = tid % 512;
  int i = io >> 5, o = io & 31;
  float2 acc = make_float2(0.f, 0.f);
  for (int p = 0; p < 24; ++p){
    float kv = ker[io*24 + p];
    float2 f = Fc[p*NLM + lm];
    acc.x += kv*f.x; acc.y += kv*f.y;
  }
  acc.x *= (float)SCALING; acc.y *= (float)SCALING;
  ycT[((size_t)(o*16 + i))*NLM + lm] = acc;
}

// ---- pipeline --------------------------------------------------------
// xf[mj][b][zi]; 4-way ILP phase recurrence
__global__ __launch_bounds__(256) void k_dft(const float* x, float2* xf){
  __shared__ float rows[4][128];
  int t = threadIdx.x, g = t >> 6, lane = t & 63;
  int r = blockIdx.x*4 + g;
  int zi = r & 255, b = r >> 8;
  const float* xr = x + ((size_t)zi*128 + b)*128;
  rows[g][lane]    = xr[lane];
  rows[g][lane+64] = xr[lane+64];
  __syncthreads();
  if (lane < NBINS){
    int m = lane - 19;
    float th = -2.0f*(float)PI_D*(float)m/128.0f;
    float sn1, cs1; sincosf(th, &sn1, &cs1);
    float cs2 = cs1*cs1 - sn1*sn1, sn2 = 2.f*cs1*sn1;
    float cs4 = cs2*cs2 - sn2*sn2, sn4 = 2.f*cs2*sn2;
    float w0r = 1.f, w0i = 0.f;
    float w1r = cs1, w1i = sn1;
    float w2r = cs2, w2i = sn2;
    float w3r = cs1*cs2 - sn1*sn2, w3i = cs1*sn2 + sn1*cs2;
    float2 a0 = make_float2(0.f,0.f), a1 = a0, a2 = a0, a3 = a0;
    const float* rw = rows[g];
    #pragma unroll 4
    for (int q = 0; q < 32; ++q){
      float v0 = rw[4*q], v1 = rw[4*q+1], v2 = rw[4*q+2], v3 = rw[4*q+3];
      a0.x += v0*w0r; a0.y += v0*w0i;
      a1.x += v1*w1r; a1.y += v1*w1i;
      a2.x += v2*w2r; a2.y += v2*w2i;
      a3.x += v3*w3r; a3.y += v3*w3i;
      float nr;
      nr = w0r*cs4 - w0i*sn4; w0i = w0r*sn4 + w0i*cs4; w0r = nr;
      nr = w1r*cs4 - w1i*sn4; w1i = w1r*sn4 + w1i*cs4; w1r = nr;
      nr = w2r*cs4 - w2i*sn4; w2i = w2r*sn4 + w2i*cs4; w2r = nr;
      nr = w3r*cs4 - w3i*sn4; w3i = w3r*sn4 + w3i*cs4; w3r = nr;
    }
    float2 acc = make_float2(a0.x+a1.x+a2.x+a3.x, a0.y+a1.y+a2.y+a3.y);
    xf[((size_t)lane*128 + b)*256 + zi] = acc;
  }
}

// partial beta-contraction: xlp[c][lm][zi], c = 32-b chunk (r7 parallel form)
__global__ void k_xlp(const float2* xf, const float* w_s2, float2* xlp){
  int lm = blockIdx.x, c = blockIdx.y, zi = threadIdx.x;
  int l = lidx(lm); int m = lm - l*l - l;
  int bin = m + 19;
  float2 acc = make_float2(0.f, 0.f);
  for (int b = c*32; b < c*32+32; ++b){
    float w = w_s2[b*NLM + lm];
    float2 v = xf[((size_t)bin*128 + b)*256 + zi];
    acc.x += w*v.x; acc.y += w*v.y;
  }
  xlp[((size_t)(c*NLM + lm))*256 + zi] = acc;
}

// sum chunks -> xlT[zi][lm]
__global__ void k_xlsum(const float2* xlp, float2* xlT){
  int lm = blockIdx.x, zi = threadIdx.x;
  float2 s = make_float2(0.f, 0.f);
  for (int c = 0; c < 4; ++c){
    float2 v = xlp[((size_t)(c*NLM + lm))*256 + zi];
    s.x += v.x; s.y += v.y;
  }
  xlT[(size_t)zi*NLM + lm] = s;
}

// zl2 in SORTED layout: z3[zo][k'], k' = lbase(l) + global pair rank
__global__ void k_zl2s(const float2* xlT, const float2* ycT, const int* ridx2,
                       float2* z3){
  int tid = blockIdx.x*256 + threadIdx.x;
  if (tid >= NZO*NPACK) return;
  int zo = tid / NPACK, k = tid % NPACK;
  int info = ridx2[k];
  int mj = info & 255, njs = (info>>8)&255, l = info>>16;
  int z = zo >> 5, o = zo & 31;
  int lmm = l*l + l + mj;
  int lmn = l*l + l + (njs - 19);
  const float2* xrow = xlT + (size_t)(z*16)*NLM;
  const float2* yrow = ycT + (size_t)(o*16)*NLM;
  float2 acc = make_float2(0.f, 0.f);
  #pragma unroll 16
  for (int i = 0; i < 16; ++i){
    float2 a  = xrow[i*NLM + lmm];
    float2 bb = yrow[i*NLM + lmn];
    acc.x += a.x*bb.x - a.y*bb.y;
    acc.y += a.x*bb.y + a.y*bb.x;
  }
  z3[tid] = acc;
}

// ---- stage 1 with z-register reuse: one thread per (zo,s), loop b ----
__global__ __launch_bounds__(256) void k_s1g(const float* dinv3, const float2* z3,
                                             const int* psort, float2* Cg){
  int tid = blockIdx.x*256 + threadIdx.x;
  if (tid >= NZO*NPAIR) return;
  int zo = tid / NPAIR, s = tid % NPAIR;
  int pk = psort[s];
  int mj = pk & 255, njs = (pk>>8)&255;
  int d_ = njs - 19, ad = d_ < 0 ? -d_ : d_;
  int lam = mj > ad ? mj : ad;
  const float2* zrow = z3 + (size_t)zo*NPACK;
  // preload z values for all l; zero slots l < lam (reads stay in-bounds:
  // lbase(l)+s <= lbase(19)+779 = 5529 < NPACK)
  float2 zr[20];
  #pragma unroll
  for (int l = 0; l < 20; ++l){
    float2 v = zrow[lbase(l) + s];
    bool act = (l >= lam);
    zr[l].x = act ? v.x : 0.f;
    zr[l].y = act ? v.y : 0.f;
  }
  for (int b = 0; b < 40; ++b){
    const float* drow = dinv3 + (size_t)b*NPACK;
    float2 c = make_float2(0.f, 0.f);
    #pragma unroll
    for (int l = 0; l < 20; ++l){
      float dv = drow[lbase(l) + s];    // coalesced in s; L2-hot (885 KB table)
      c.x += dv*zr[l].x;                // zr[l]=0 for l<lam -> no-op
      c.y += dv*zr[l].y;
    }
    Cg[((size_t)(zo*40 + b))*NPAIR + s] = c;   // coalesced, sorted order
  }
}

// ---- synthesis stages 2+3: block = (zo, 2b), radix-4 output folding --
__global__ __launch_bounds__(512) void k_s2(const float2* Cg, const int* psort,
                                            const float2* wsyn, const float* bias,
                                            float* out){
  __shared__ float2 Cs[2][NPAIR];     // 12.48 KB
  __shared__ float2 Gs[2][800];       // 12.8 KB
  __shared__ float2 Wq[390];          // [njs][g0<10]  3.12 KB
  __shared__ float2 Wma[200];         // [mj][a0<10]   1.6 KB  -> 30 KB
  int blk = blockIdx.x;               // zo*20 + bg
  int zo = blk / 20, bg = blk % 20;
  int b0 = bg*2;
  int o = zo & 31;
  int t = threadIdx.x;

  const float2* crow = Cg + (size_t)(zo*40 + b0)*NPAIR;
  for (int idx = t; idx < 2*NPAIR; idx += 512){
    int b_ = idx / NPAIR, p = idx % NPAIR;
    int pk = psort[p];
    Cs[b_][(pk&255)*39 + ((pk>>8)&255)] = crow[b_*NPAIR + p];
  }
  for (int idx = t; idx < 390; idx += 512){
    int njs = idx/10, g0 = idx%10;
    Wq[idx] = wsyn[njs*40 + g0];
  }
  for (int idx = t; idx < 200; idx += 512){
    int mj = idx/10, a0 = idx%10;
    Wma[idx] = wsyn[(19+mj)*40 + a0];
  }
  __syncthreads();

  // stage 2: G[mj][g0+10k] = sum_r i^{rk} S_r,  S_r over njs-residue classes
  if (t < 400){
    int b_ = t / 200, r2 = t % 200;
    int mj = r2 / 10, g0 = r2 % 10;
    const float2* cr = Cs[b_] + mj*39;
    float2 S0 = make_float2(0.f,0.f), S1 = S0, S2 = S0, S3 = S0;
    for (int j = 0; j < 9; ++j){        // r=0: njs = 3+4j
      float2 c = cr[3+4*j]; float2 w = Wq[(3+4*j)*10 + g0];
      S0.x += c.x*w.x - c.y*w.y; S0.y += c.x*w.y + c.y*w.x;
    }
    for (int j = 0; j < 10; ++j){       // r=1: njs = 4j
      float2 c = cr[4*j]; float2 w = Wq[(4*j)*10 + g0];
      S1.x += c.x*w.x - c.y*w.y; S1.y += c.x*w.y + c.y*w.x;
    }
    for (int j = 0; j < 10; ++j){       // r=2: njs = 1+4j
      float2 c = cr[1+4*j]; float2 w = Wq[(1+4*j)*10 + g0];
      S2.x += c.x*w.x - c.y*w.y; S2.y += c.x*w.y + c.y*w.x;
    }
    for (int j = 0; j < 10; ++j){       // r=3: njs = 2+4j
      float2 c = cr[2+4*j]; float2 w = Wq[(2+4*j)*10 + g0];
      S3.x += c.x*w.x - c.y*w.y; S3.y += c.x*w.y + c.y*w.x;
    }
    float2* gb = Gs[b_];
    gb[mj*40 + g0     ] = make_float2(S0.x+S1.x+S2.x+S3.x, S0.y+S1.y+S2.y+S3.y);
    gb[mj*40 + g0 + 10] = make_float2(S0.x-S1.y-S2.x+S3.y, S0.y+S1.x-S2.y-S3.x);
    gb[mj*40 + g0 + 20] = make_float2(S0.x-S1.x+S2.x-S3.x, S0.y-S1.y+S2.y-S3.y);
    gb[mj*40 + g0 + 30] = make_float2(S0.x+S1.y-S2.x-S3.y, S0.y-S1.x-S2.y+S3.x);
  }
  __syncthreads();

  // stage 3: out[a0+10k][g] = G0[g].x + 2 Re(sum_r i^{rk} S_r) + bias
  float bv = bias[o];
  for (int idx = t; idx < 800; idx += 512){
    int b_ = idx / 400, r3 = idx % 400;
    int a0 = r3 / 40, g = r3 % 40;
    const float2* gb = Gs[b_];
    float S0x = 0.f, S2x = 0.f;
    float2 S1 = make_float2(0.f,0.f), S3 = S1;
    for (int j = 0; j < 4; ++j){        // r=0: mj = 4+4j
      float2 gv = gb[(4+4*j)*40 + g]; float2 w = Wma[(4+4*j)*10 + a0];
      S0x += gv.x*w.x - gv.y*w.y;
    }
    for (int j = 0; j < 5; ++j){        // r=1: mj = 1+4j
      float2 gv = gb[(1+4*j)*40 + g]; float2 w = Wma[(1+4*j)*10 + a0];
      S1.x += gv.x*w.x - gv.y*w.y; S1.y += gv.x*w.y + gv.y*w.x;
    }
    for (int j = 0; j < 5; ++j){        // r=2: mj = 2+4j
      float2 gv = gb[(2+4*j)*40 + g]; float2 w = Wma[(2+4*j)*10 + a0];
      S2x += gv.x*w.x - gv.y*w.y;
    }
    for (int j = 0; j < 5; ++j){        // r=3: mj = 3+4j
      float2 gv = gb[(3+4*j)*40 + g]; float2 w = Wma[(3+4*j)*10 + a0];
      S3.x += gv.x*w.x - gv.y*w.y; S3.y += gv.x*w.y + gv.y*w.x;
    }
    float g0v = gb[g].x;
    float* orow = out + ((size_t)zo*40 + b0 + b_)*1600;
    orow[(a0     )*40 + g] = g0v + 2.f*(S0x + S1.x + S2x + S3.x) + bv;
    orow[(a0 + 10)*40 + g] = g0v + 2.f*(S0x - S1.y - S2x + S3.y) + bv;
    orow[(a0 + 20)*40 + g] = g0v + 2.f*(S0x - S1.x + S2x - S3.x) + bv;
    orow[(a0 + 30)*40 + g] = g0v + 2.f*(S0x + S1.y - S2x - S3.y) + bv;
  }
}

extern "C" void kernel_launch(void* const* d_in, const int* in_sizes, int n_in,
                              void* d_out, int out_size, void* d_ws, size_t ws_size,
                              hipStream_t stream) {
  const float* x    = (const float*)d_in[0];
  const float* ker  = (const float*)d_in[1];
  const float* bias = (const float*)d_in[2];
  float* out = (float*)d_out;

  char* ws = (char*)d_ws;
  size_t cur = 0;
  auto alloc = [&](size_t bytes)->char*{
    char* p = ws + cur;
    cur += (bytes + 255) & ~(size_t)255;
    return p;
  };
  double* lg    = (double*)alloc(64*8);
  double* wq    = (double*)alloc(128*8);
  int*    psort = (int*)   alloc(NPAIR*4);
  int*    ridx2 = (int*)   alloc(NPACK*4);
  float2* wsyn  = (float2*)alloc((size_t)1560*8);
  float*  w_s2  = (float*) alloc((size_t)NB_IN*NLM*4);
  float*  dinv3 = (float*) alloc((size_t)TWOB*NPACK*4);
  float2* Fc    = (float2*)alloc((size_t)24*NLM*8);
  float2* ycT   = (float2*)alloc((size_t)512*400*8);
  float2* xf    = (float2*)alloc((size_t)NBINS*128*256*8);
  float2* xlp   = (float2*)alloc((size_t)4*NLM*256*8);
  float2* xlT   = (float2*)alloc((size_t)256*NLM*8);
  float2* z3    = (float2*)alloc((size_t)NZO*NPACK*8);      // 45 MB
  float2* Cg    = (float2*)alloc((size_t)NZO*40*NPAIR*8);   // 128 MB
  (void)ws_size; (void)in_sizes; (void)n_in; (void)out_size;

  k_init  <<<1, 256, 0, stream>>>(lg, wq, psort, ridx2, wsyn);
  k_tables<<<671, 256, 0, stream>>>(w_s2, dinv3, Fc, ridx2, lg, wq);
  k_yc    <<<800, 256, 0, stream>>>(ker, Fc, ycT);

  k_dft  <<<(256*128)/4, 256, 0, stream>>>(x, xf);
  k_xlp  <<<dim3(NLM, 4), 256, 0, stream>>>(xf, w_s2, xlp);
  k_xlsum<<<NLM, 256, 0, stream>>>(xlp, xlT);
  k_zl2s <<<(NZO*NPACK + 255)/256, 256, 0, stream>>>(xlT, ycT, ridx2, z3);
  k_s1g  <<<(NZO*NPAIR + 255)/256, 256, 0, stream>>>(dinv3, z3, psort, Cg);
  k_s2   <<<NZO*20, 512, 0, stream>>>(Cg, psort, wsyn, bias, out);
}

// Round 25
// 347.483 us; speedup vs baseline: 1.7263x; 1.1411x over previous
//
#include <hip/hip_runtime.h>
#include <math.h>

#define NB_IN   128
#define NBINS   39
#define NLM     400
#define NZO     512
#define NPAIR   780
#define NPACK   5530
#define TWOB    40
#define PI_D    3.14159265358979323846
#define SCALING 0.008164965809277261

// lbase(l) = sum_{l'<l} (2l'+1)(l'+1);  lbase(20) = 5530
__host__ __device__ __forceinline__ int lbase(int l){
  return l*(l-1)*(2*l-1)/3 + 3*l*(l-1)/2 + l;
}

__device__ __forceinline__ int lidx(int lm){
  int l = (int)sqrtf((float)lm);
  while ((l+1)*(l+1) <= lm) ++l;
  while (l*l > lm) --l;
  return l;
}

// Wigner little-d via Jacobi sum (one-shot)
__device__ double wigner_d(int l, int m, int n, double beta, const double* lg){
  double cb = cos(0.5*beta), sb = sin(0.5*beta);
  double lcb = log(cb), lsb = log(sb);
  double pref = 0.5*(lg[l+m]+lg[l-m]+lg[l+n]+lg[l-n]);
  int s0 = 0 > (n-m) ? 0 : (n-m);
  int s1 = (l+n) < (l-m) ? (l+n) : (l-m);
  double val = 0.0;
  for (int s = s0; s <= s1; ++s){
    double c = pref - (lg[l+n-s]+lg[s]+lg[m-n+s]+lg[l-m-s]);
    double t = exp(c + (double)(2*l+n-m-2*s)*lcb + (double)(m-n+2*s)*lsb);
    val += ((m-n+s)&1) ? -t : t;
  }
  return val;
}

// fast Wigner: 2 log + 1 exp + ratio recurrence over s (fp64)
__device__ double wigner_fast(int l, int m, int n, double beta, const double* lg){
  double cb = cos(0.5*beta), sb = sin(0.5*beta);
  double lcb = log(cb), lsb = log(sb);
  double pref = 0.5*(lg[l+m]+lg[l-m]+lg[l+n]+lg[l-n]);
  int s0 = 0 > (n-m) ? 0 : (n-m);
  int s1 = (l+n) < (l-m) ? (l+n) : (l-m);
  double ratio = (sb*sb)/(cb*cb);
  double t = exp(pref - (lg[l+n-s0]+lg[s0]+lg[m-n+s0]+lg[l-m-s0])
               + (double)(2*l+n-m-2*s0)*lcb + (double)(m-n+2*s0)*lsb);
  double sgn = ((m-n+s0)&1) ? -1.0 : 1.0;
  double acc = 0.0;
  for (int s = s0; s <= s1; ++s){
    acc += sgn*t;
    sgn = -sgn;
    t *= ratio * ((double)((l+n-s)*(l-m-s)) / (double)((s+1)*(m-n+s+1)));
  }
  return acc;
}

// ---- constants: k_init (lg, wq, psort, ridx2, wsyn) ------------------
__global__ void k_init(double* lg, double* wq, int* psort, int* ridx2, float2* wsyn){
  int t = threadIdx.x;  // 256
  if (t == 0){
    lg[0] = 0.0; double acc = 0.0;
    for (int k = 1; k <= 40; ++k){ acc += log((double)k); lg[k] = acc; }
  }
  for (int p = t; p < NPAIR; p += 256){
    int mj = p/39, njs = p%39, d = njs-19, ad = d<0?-d:d;
    int lam = mj > ad ? mj : ad;
    int pre = (lam==0) ? 0 : (2*lam-1)*lam;
    int rank = (mj < lam) ? (2*mj + ((njs==19+lam)?1:0))
                          : (2*lam + (njs-(19-lam)));
    int R = pre + rank;                   // global sorted rank
    psort[R] = mj | (njs<<8);
    int info = mj | (njs<<8);
    for (int l = lam; l < 20; ++l)
      ridx2[lbase(l) + R] = info | (l<<16);
  }
  if (t < 128){
    double theta = PI_D*(2*t+1)/256.0;
    double s = 0.0;
    for (int k = 0; k < 64; ++k) s += sin((2*k+1)*theta)/(double)(2*k+1);
    wq[t] = (2.0/64.0)*sin(theta)*s;
  }
  // wsyn[njs*40+g] = e^{i (njs-19) g 2pi/40}; Wm[mj][a] = wsyn[(19+mj)*40+a]
  for (int idx = t; idx < 1560; idx += 256){
    int njs = idx/40, g = idx%40;
    double ang = 2.0*PI_D*(double)(njs-19)*(double)g/40.0;
    wsyn[idx] = make_float2((float)cos(ang), (float)sin(ang));
  }
}

// ---- fused tables: [0,200) ws2 | [200,633) dinv3 sorted layout | [633,671) Fc
__global__ void k_tables(float* w_s2, float* dinv3, float2* Fc,
                         const int* ridx2, const double* lg, const double* wq){
  int bid = blockIdx.x, t = threadIdx.x;
  if (bid < 200){
    int tid = bid*256 + t;            // one eval per thread
    if (tid >= 128*NLM) return;
    int b = tid / NLM, lm = tid % NLM;
    int l = lidx(lm); int m = lm - l*l - l;
    double beta = PI_D*(2*b+1)/256.0;
    w_s2[b*NLM + lm] = (float)(wigner_fast(l, m, 0, beta, lg) * wq[b]);
  } else if (bid < 633){
    int idx = (bid-200)*256 + t;      // one eval per thread; b in [0,20)
    if (idx >= 20*NPACK) return;
    int b = idx / NPACK, k = idx % NPACK;
    int info = ridx2[k];
    int mj = info & 255, njs = (info>>8)&255, l = info>>16;
    int n = njs - 19, ad = n < 0 ? -n : n;
    int lam = mj > ad ? mj : ad;
    int pre = (lam==0) ? 0 : (2*lam-1)*lam;
    int rank_m = (mj < lam) ? (2*mj + ((njs == 19-lam) ? 1 : 0))
                            : (2*lam + (19 + lam - njs));
    float sgn = ((l+mj)&1) ? -1.f : 1.f;
    double beta = PI_D*(2*b+1)/80.0;
    float v = (float)((double)(2*l+1) * wigner_fast(l, mj, n, beta, lg));
    dinv3[b*NPACK + k] = v;
    dinv3[(39-b)*NPACK + lbase(l) + pre + rank_m] = sgn * v;  // d(pi-b) identity
  } else {
    int tid = (bid-633)*256 + t;
    if (tid >= 24*NLM) return;
    int p = tid / NLM, lm = tid % NLM;
    int l = lidx(lm); int m = lm - l*l - l;
    double beta = PI_D*(double)(p/8 + 1)/24.0;
    double alpha = (double)(p%8)*(PI_D/4.0);
    double d = wigner_d(l, m, 0, beta, lg);
    double a = (double)m*alpha;            // conj(F_k)
    Fc[tid] = make_float2((float)(d*cos(a)), (float)(d*sin(a)));
  }
}

__global__ void k_yc(const float* ker, const float2* Fc, float2* ycT){
  int tid = blockIdx.x*256 + threadIdx.x;
  if (tid >= NLM*NZO) return;
  int lm = tid / 512, io = tid % 512;
  int i = io >> 5, o = io & 31;
  float2 acc = make_float2(0.f, 0.f);
  for (int p = 0; p < 24; ++p){
    float kv = ker[io*24 + p];
    float2 f = Fc[p*NLM + lm];
    acc.x += kv*f.x; acc.y += kv*f.y;
  }
  acc.x *= (float)SCALING; acc.y *= (float)SCALING;
  ycT[((size_t)(o*16 + i))*NLM + lm] = acc;
}

// ---- pipeline --------------------------------------------------------
// xf[mj][b][zi]; 4-way ILP phase recurrence
__global__ __launch_bounds__(256) void k_dft(const float* x, float2* xf){
  __shared__ float rows[4][128];
  int t = threadIdx.x, g = t >> 6, lane = t & 63;
  int r = blockIdx.x*4 + g;
  int zi = r & 255, b = r >> 8;
  const float* xr = x + ((size_t)zi*128 + b)*128;
  rows[g][lane]    = xr[lane];
  rows[g][lane+64] = xr[lane+64];
  __syncthreads();
  if (lane < NBINS){
    int m = lane - 19;
    float th = -2.0f*(float)PI_D*(float)m/128.0f;
    float sn1, cs1; sincosf(th, &sn1, &cs1);
    float cs2 = cs1*cs1 - sn1*sn1, sn2 = 2.f*cs1*sn1;
    float cs4 = cs2*cs2 - sn2*sn2, sn4 = 2.f*cs2*sn2;
    float w0r = 1.f, w0i = 0.f;
    float w1r = cs1, w1i = sn1;
    float w2r = cs2, w2i = sn2;
    float w3r = cs1*cs2 - sn1*sn2, w3i = cs1*sn2 + sn1*cs2;
    float2 a0 = make_float2(0.f,0.f), a1 = a0, a2 = a0, a3 = a0;
    const float* rw = rows[g];
    #pragma unroll 4
    for (int q = 0; q < 32; ++q){
      float v0 = rw[4*q], v1 = rw[4*q+1], v2 = rw[4*q+2], v3 = rw[4*q+3];
      a0.x += v0*w0r; a0.y += v0*w0i;
      a1.x += v1*w1r; a1.y += v1*w1i;
      a2.x += v2*w2r; a2.y += v2*w2i;
      a3.x += v3*w3r; a3.y += v3*w3i;
      float nr;
      nr = w0r*cs4 - w0i*sn4; w0i = w0r*sn4 + w0i*cs4; w0r = nr;
      nr = w1r*cs4 - w1i*sn4; w1i = w1r*sn4 + w1i*cs4; w1r = nr;
      nr = w2r*cs4 - w2i*sn4; w2i = w2r*sn4 + w2i*cs4; w2r = nr;
      nr = w3r*cs4 - w3i*sn4; w3i = w3r*sn4 + w3i*cs4; w3r = nr;
    }
    float2 acc = make_float2(a0.x+a1.x+a2.x+a3.x, a0.y+a1.y+a2.y+a3.y);
    xf[((size_t)lane*128 + b)*256 + zi] = acc;
  }
}

// partial beta-contraction: xlp[c][lm][zi], c = 32-b chunk (r7 parallel form)
__global__ void k_xlp(const float2* xf, const float* w_s2, float2* xlp){
  int lm = blockIdx.x, c = blockIdx.y, zi = threadIdx.x;
  int l = lidx(lm); int m = lm - l*l - l;
  int bin = m + 19;
  float2 acc = make_float2(0.f, 0.f);
  for (int b = c*32; b < c*32+32; ++b){
    float w = w_s2[b*NLM + lm];
    float2 v = xf[((size_t)bin*128 + b)*256 + zi];
    acc.x += w*v.x; acc.y += w*v.y;
  }
  xlp[((size_t)(c*NLM + lm))*256 + zi] = acc;
}

// sum chunks -> xlT[zi][lm]
__global__ void k_xlsum(const float2* xlp, float2* xlT){
  int lm = blockIdx.x, zi = threadIdx.x;
  float2 s = make_float2(0.f, 0.f);
  for (int c = 0; c < 4; ++c){
    float2 v = xlp[((size_t)(c*NLM + lm))*256 + zi];
    s.x += v.x; s.y += v.y;
  }
  xlT[(size_t)zi*NLM + lm] = s;
}

// zl2 in SORTED layout: z3[zo][k'], k' = lbase(l) + global pair rank
__global__ void k_zl2s(const float2* xlT, const float2* ycT, const int* ridx2,
                       float2* z3){
  int tid = blockIdx.x*256 + threadIdx.x;
  if (tid >= NZO*NPACK) return;
  int zo = tid / NPACK, k = tid % NPACK;
  int info = ridx2[k];
  int mj = info & 255, njs = (info>>8)&255, l = info>>16;
  int z = zo >> 5, o = zo & 31;
  int lmm = l*l + l + mj;
  int lmn = l*l + l + (njs - 19);
  const float2* xrow = xlT + (size_t)(z*16)*NLM;
  const float2* yrow = ycT + (size_t)(o*16)*NLM;
  float2 acc = make_float2(0.f, 0.f);
  #pragma unroll 16
  for (int i = 0; i < 16; ++i){
    float2 a  = xrow[i*NLM + lmm];
    float2 bb = yrow[i*NLM + lmn];
    acc.x += a.x*bb.x - a.y*bb.y;
    acc.y += a.x*bb.y + a.y*bb.x;
  }
  z3[tid] = acc;
}

// ---- stage 1 with z-register reuse: one thread per (zo,s), loop b ----
__global__ __launch_bounds__(256) void k_s1g(const float* dinv3, const float2* z3,
                                             const int* psort, float2* Cg){
  int tid = blockIdx.x*256 + threadIdx.x;
  if (tid >= NZO*NPAIR) return;
  int zo = tid / NPAIR, s = tid % NPAIR;
  int pk = psort[s];
  int mj = pk & 255, njs = (pk>>8)&255;
  int d_ = njs - 19, ad = d_ < 0 ? -d_ : d_;
  int lam = mj > ad ? mj : ad;
  const float2* zrow = z3 + (size_t)zo*NPACK;
  float2 zr[20];
  #pragma unroll
  for (int l = 0; l < 20; ++l){
    float2 v = zrow[lbase(l) + s];
    bool act = (l >= lam);
    zr[l].x = act ? v.x : 0.f;
    zr[l].y = act ? v.y : 0.f;
  }
  for (int b = 0; b < 40; ++b){
    const float* drow = dinv3 + (size_t)b*NPACK;
    float2 c = make_float2(0.f, 0.f);
    #pragma unroll
    for (int l = 0; l < 20; ++l){
      float dv = drow[lbase(l) + s];
      c.x += dv*zr[l].x;
      c.y += dv*zr[l].y;
    }
    Cg[((size_t)(zo*40 + b))*NPAIR + s] = c;   // coalesced, sorted order
  }
}

// ---- synthesis stages 2+3: block = (zo, 2b) with 256 threads ---------
// (4-wave blocks: VGPR-granularity allows 4 resident blocks/CU vs 2 at 512)
__global__ __launch_bounds__(256) void k_s2(const float2* Cg, const int* psort,
                                            const float2* wsyn, const float* bias,
                                            float* out){
  __shared__ float2 Cs[2][NPAIR];     // 12.48 KB
  __shared__ float2 Gs[2][800];       // 12.8 KB
  __shared__ float2 Wq[390];          // [njs][g0<10]  3.12 KB
  __shared__ float2 Wma[200];         // [mj][a0<10]   1.6 KB  -> 30 KB
  int blk = blockIdx.x;               // zo*20 + bg
  int zo = blk / 20, bg = blk % 20;
  int b0 = bg*2;
  int o = zo & 31;
  int t = threadIdx.x;

  const float2* crow = Cg + (size_t)(zo*40 + b0)*NPAIR;
  for (int idx = t; idx < 2*NPAIR; idx += 256){
    int b_ = idx / NPAIR, p = idx % NPAIR;
    int pk = psort[p];
    Cs[b_][(pk&255)*39 + ((pk>>8)&255)] = crow[b_*NPAIR + p];
  }
  for (int idx = t; idx < 390; idx += 256){
    int njs = idx/10, g0 = idx%10;
    Wq[idx] = wsyn[njs*40 + g0];
  }
  for (int idx = t; idx < 200; idx += 256){
    int mj = idx/10, a0 = idx%10;
    Wma[idx] = wsyn[(19+mj)*40 + a0];
  }
  __syncthreads();

  // stage 2: G[mj][g0+10k] = sum_r i^{rk} S_r,  S_r over njs-residue classes
  for (int it = t; it < 400; it += 256){
    int b_ = it / 200, r2 = it % 200;
    int mj = r2 / 10, g0 = r2 % 10;
    const float2* cr = Cs[b_] + mj*39;
    float2 S0 = make_float2(0.f,0.f), S1 = S0, S2 = S0, S3 = S0;
    for (int j = 0; j < 9; ++j){        // r=0: njs = 3+4j
      float2 c = cr[3+4*j]; float2 w = Wq[(3+4*j)*10 + g0];
      S0.x += c.x*w.x - c.y*w.y; S0.y += c.x*w.y + c.y*w.x;
    }
    for (int j = 0; j < 10; ++j){       // r=1: njs = 4j
      float2 c = cr[4*j]; float2 w = Wq[(4*j)*10 + g0];
      S1.x += c.x*w.x - c.y*w.y; S1.y += c.x*w.y + c.y*w.x;
    }
    for (int j = 0; j < 10; ++j){       // r=2: njs = 1+4j
      float2 c = cr[1+4*j]; float2 w = Wq[(1+4*j)*10 + g0];
      S2.x += c.x*w.x - c.y*w.y; S2.y += c.x*w.y + c.y*w.x;
    }
    for (int j = 0; j < 10; ++j){       // r=3: njs = 2+4j
      float2 c = cr[2+4*j]; float2 w = Wq[(2+4*j)*10 + g0];
      S3.x += c.x*w.x - c.y*w.y; S3.y += c.x*w.y + c.y*w.x;
    }
    float2* gb = Gs[b_];
    gb[mj*40 + g0     ] = make_float2(S0.x+S1.x+S2.x+S3.x, S0.y+S1.y+S2.y+S3.y);
    gb[mj*40 + g0 + 10] = make_float2(S0.x-S1.y-S2.x+S3.y, S0.y+S1.x-S2.y-S3.x);
    gb[mj*40 + g0 + 20] = make_float2(S0.x-S1.x+S2.x-S3.x, S0.y-S1.y+S2.y-S3.y);
    gb[mj*40 + g0 + 30] = make_float2(S0.x+S1.y-S2.x-S3.y, S0.y-S1.x-S2.y+S3.x);
  }
  __syncthreads();

  // stage 3: out[a0+10k][g] = G0[g].x + 2 Re(sum_r i^{rk} S_r) + bias
  float bv = bias[o];
  for (int idx = t; idx < 800; idx += 256){
    int b_ = idx / 400, r3 = idx % 400;
    int a0 = r3 / 40, g = r3 % 40;
    const float2* gb = Gs[b_];
    float S0x = 0.f, S2x = 0.f;
    float2 S1 = make_float2(0.f,0.f), S3 = S1;
    for (int j = 0; j < 4; ++j){        // r=0: mj = 4+4j
      float2 gv = gb[(4+4*j)*40 + g]; float2 w = Wma[(4+4*j)*10 + a0];
      S0x += gv.x*w.x - gv.y*w.y;
    }
    for (int j = 0; j < 5; ++j){        // r=1: mj = 1+4j
      float2 gv = gb[(1+4*j)*40 + g]; float2 w = Wma[(1+4*j)*10 + a0];
      S1.x += gv.x*w.x - gv.y*w.y; S1.y += gv.x*w.y + gv.y*w.x;
    }
    for (int j = 0; j < 5; ++j){        // r=2: mj = 2+4j
      float2 gv = gb[(2+4*j)*40 + g]; float2 w = Wma[(2+4*j)*10 + a0];
      S2x += gv.x*w.x - gv.y*w.y;
    }
    for (int j = 0; j < 5; ++j){        // r=3: mj = 3+4j
      float2 gv = gb[(3+4*j)*40 + g]; float2 w = Wma[(3+4*j)*10 + a0];
      S3.x += gv.x*w.x - gv.y*w.y; S3.y += gv.x*w.y + gv.y*w.x;
    }
    float g0v = gb[g].x;
    float* orow = out + ((size_t)zo*40 + b0 + b_)*1600;
    orow[(a0     )*40 + g] = g0v + 2.f*(S0x + S1.x + S2x + S3.x) + bv;
    orow[(a0 + 10)*40 + g] = g0v + 2.f*(S0x - S1.y - S2x + S3.y) + bv;
    orow[(a0 + 20)*40 + g] = g0v + 2.f*(S0x - S1.x + S2x - S3.x) + bv;
    orow[(a0 + 30)*40 + g] = g0v + 2.f*(S0x + S1.y - S2x - S3.y) + bv;
  }
}

extern "C" void kernel_launch(void* const* d_in, const int* in_sizes, int n_in,
                              void* d_out, int out_size, void* d_ws, size_t ws_size,
                              hipStream_t stream) {
  const float* x    = (const float*)d_in[0];
  const float* ker  = (const float*)d_in[1];
  const float* bias = (const float*)d_in[2];
  float* out = (float*)d_out;

  char* ws = (char*)d_ws;
  size_t cur = 0;
  auto alloc = [&](size_t bytes)->char*{
    char* p = ws + cur;
    cur += (bytes + 255) & ~(size_t)255;
    return p;
  };
  double* lg    = (double*)alloc(64*8);
  double* wq    = (double*)alloc(128*8);
  int*    psort = (int*)   alloc(NPAIR*4);
  int*    ridx2 = (int*)   alloc(NPACK*4);
  float2* wsyn  = (float2*)alloc((size_t)1560*8);
  float*  w_s2  = (float*) alloc((size_t)NB_IN*NLM*4);
  float*  dinv3 = (float*) alloc((size_t)TWOB*NPACK*4);
  float2* Fc    = (float2*)alloc((size_t)24*NLM*8);
  float2* ycT   = (float2*)alloc((size_t)512*400*8);
  float2* xf    = (float2*)alloc((size_t)NBINS*128*256*8);
  float2* xlp   = (float2*)alloc((size_t)4*NLM*256*8);
  float2* xlT   = (float2*)alloc((size_t)256*NLM*8);
  float2* z3    = (float2*)alloc((size_t)NZO*NPACK*8);      // 45 MB
  float2* Cg    = (float2*)alloc((size_t)NZO*40*NPAIR*8);   // 128 MB
  (void)ws_size; (void)in_sizes; (void)n_in; (void)out_size;

  k_init  <<<1, 256, 0, stream>>>(lg, wq, psort, ridx2, wsyn);
  k_tables<<<671, 256, 0, stream>>>(w_s2, dinv3, Fc, ridx2, lg, wq);
  k_yc    <<<800, 256, 0, stream>>>(ker, Fc, ycT);

  k_dft  <<<(256*128)/4, 256, 0, stream>>>(x, xf);
  k_xlp  <<<dim3(NLM, 4), 256, 0, stream>>>(xf, w_s2, xlp);
  k_xlsum<<<NLM, 256, 0, stream>>>(xlp, xlT);
  k_zl2s <<<(NZO*NPACK + 255)/256, 256, 0, stream>>>(xlT, ycT, ridx2, z3);
  k_s1g  <<<(NZO*NPAIR + 255)/256, 256, 0, stream>>>(dinv3, z3, psort, Cg);
  k_s2   <<<NZO*20, 256, 0, stream>>>(Cg, psort, wsyn, bias, out);
}

// Round 26
// 347.134 us; speedup vs baseline: 1.7281x; 1.0010x over previous
//
#include <hip/hip_runtime.h>
#include <math.h>

#define NB_IN   128
#define NBINS   39
#define NLM     400
#define NZO     512
#define NPAIR   780
#define NPACK   5530
#define TWOB    40
#define PI_D    3.14159265358979323846
#define SCALING 0.008164965809277261

// lbase(l) = sum_{l'<l} (2l'+1)(l'+1);  lbase(20) = 5530
__host__ __device__ __forceinline__ int lbase(int l){
  return l*(l-1)*(2*l-1)/3 + 3*l*(l-1)/2 + l;
}

__device__ __forceinline__ int lidx(int lm){
  int l = (int)sqrtf((float)lm);
  while ((l+1)*(l+1) <= lm) ++l;
  while (l*l > lm) --l;
  return l;
}

// Wigner little-d via Jacobi sum (one-shot)
__device__ double wigner_d(int l, int m, int n, double beta, const double* lg){
  double cb = cos(0.5*beta), sb = sin(0.5*beta);
  double lcb = log(cb), lsb = log(sb);
  double pref = 0.5*(lg[l+m]+lg[l-m]+lg[l+n]+lg[l-n]);
  int s0 = 0 > (n-m) ? 0 : (n-m);
  int s1 = (l+n) < (l-m) ? (l+n) : (l-m);
  double val = 0.0;
  for (int s = s0; s <= s1; ++s){
    double c = pref - (lg[l+n-s]+lg[s]+lg[m-n+s]+lg[l-m-s]);
    double t = exp(c + (double)(2*l+n-m-2*s)*lcb + (double)(m-n+2*s)*lsb);
    val += ((m-n+s)&1) ? -t : t;
  }
  return val;
}

// fast Wigner: 2 log + 1 exp + ratio recurrence over s (fp64)
__device__ double wigner_fast(int l, int m, int n, double beta, const double* lg){
  double cb = cos(0.5*beta), sb = sin(0.5*beta);
  double lcb = log(cb), lsb = log(sb);
  double pref = 0.5*(lg[l+m]+lg[l-m]+lg[l+n]+lg[l-n]);
  int s0 = 0 > (n-m) ? 0 : (n-m);
  int s1 = (l+n) < (l-m) ? (l+n) : (l-m);
  double ratio = (sb*sb)/(cb*cb);
  double t = exp(pref - (lg[l+n-s0]+lg[s0]+lg[m-n+s0]+lg[l-m-s0])
               + (double)(2*l+n-m-2*s0)*lcb + (double)(m-n+2*s0)*lsb);
  double sgn = ((m-n+s0)&1) ? -1.0 : 1.0;
  double acc = 0.0;
  for (int s = s0; s <= s1; ++s){
    acc += sgn*t;
    sgn = -sgn;
    t *= ratio * ((double)((l+n-s)*(l-m-s)) / (double)((s+1)*(m-n+s+1)));
  }
  return acc;
}

// ---- constants: k_init (lg, wq, psort, ridx2, wsyn) ------------------
__global__ void k_init(double* lg, double* wq, int* psort, int* ridx2, float2* wsyn){
  int t = threadIdx.x;  // 256
  if (t == 0){
    lg[0] = 0.0; double acc = 0.0;
    for (int k = 1; k <= 40; ++k){ acc += log((double)k); lg[k] = acc; }
  }
  for (int p = t; p < NPAIR; p += 256){
    int mj = p/39, njs = p%39, d = njs-19, ad = d<0?-d:d;
    int lam = mj > ad ? mj : ad;
    int pre = (lam==0) ? 0 : (2*lam-1)*lam;
    int rank = (mj < lam) ? (2*mj + ((njs==19+lam)?1:0))
                          : (2*lam + (njs-(19-lam)));
    int R = pre + rank;                   // global sorted rank
    psort[R] = mj | (njs<<8);
    int info = mj | (njs<<8);
    for (int l = lam; l < 20; ++l)
      ridx2[lbase(l) + R] = info | (l<<16);
  }
  if (t < 128){
    double theta = PI_D*(2*t+1)/256.0;
    double s = 0.0;
    for (int k = 0; k < 64; ++k) s += sin((2*k+1)*theta)/(double)(2*k+1);
    wq[t] = (2.0/64.0)*sin(theta)*s;
  }
  // wsyn[njs*40+g] = e^{i (njs-19) g 2pi/40}; Wm[mj][a] = wsyn[(19+mj)*40+a]
  for (int idx = t; idx < 1560; idx += 256){
    int njs = idx/40, g = idx%40;
    double ang = 2.0*PI_D*(double)(njs-19)*(double)g/40.0;
    wsyn[idx] = make_float2((float)cos(ang), (float)sin(ang));
  }
}

// ---- fused tables: [0,200) ws2 | [200,633) dinv3 sorted layout | [633,671) Fc
__global__ void k_tables(float* w_s2, float* dinv3, float2* Fc,
                         const int* ridx2, const double* lg, const double* wq){
  int bid = blockIdx.x, t = threadIdx.x;
  if (bid < 200){
    int tid = bid*256 + t;            // one eval per thread
    if (tid >= 128*NLM) return;
    int b = tid / NLM, lm = tid % NLM;
    int l = lidx(lm); int m = lm - l*l - l;
    double beta = PI_D*(2*b+1)/256.0;
    w_s2[b*NLM + lm] = (float)(wigner_fast(l, m, 0, beta, lg) * wq[b]);
  } else if (bid < 633){
    int idx = (bid-200)*256 + t;      // one eval per thread; b in [0,20)
    if (idx >= 20*NPACK) return;
    int b = idx / NPACK, k = idx % NPACK;
    int info = ridx2[k];
    int mj = info & 255, njs = (info>>8)&255, l = info>>16;
    int n = njs - 19, ad = n < 0 ? -n : n;
    int lam = mj > ad ? mj : ad;
    int pre = (lam==0) ? 0 : (2*lam-1)*lam;
    int rank_m = (mj < lam) ? (2*mj + ((njs == 19-lam) ? 1 : 0))
                            : (2*lam + (19 + lam - njs));
    float sgn = ((l+mj)&1) ? -1.f : 1.f;
    double beta = PI_D*(2*b+1)/80.0;
    float v = (float)((double)(2*l+1) * wigner_fast(l, mj, n, beta, lg));
    dinv3[b*NPACK + k] = v;
    dinv3[(39-b)*NPACK + lbase(l) + pre + rank_m] = sgn * v;  // d(pi-b) identity
  } else {
    int tid = (bid-633)*256 + t;
    if (tid >= 24*NLM) return;
    int p = tid / NLM, lm = tid % NLM;
    int l = lidx(lm); int m = lm - l*l - l;
    double beta = PI_D*(double)(p/8 + 1)/24.0;
    double alpha = (double)(p%8)*(PI_D/4.0);
    double d = wigner_d(l, m, 0, beta, lg);
    double a = (double)m*alpha;            // conj(F_k)
    Fc[tid] = make_float2((float)(d*cos(a)), (float)(d*sin(a)));
  }
}

__global__ void k_yc(const float* ker, const float2* Fc, float2* ycT){
  int tid = blockIdx.x*256 + threadIdx.x;
  if (tid >= NLM*NZO) return;
  int lm = tid / 512, io = tid % 512;
  int i = io >> 5, o = io & 31;
  float2 acc = make_float2(0.f, 0.f);
  for (int p = 0; p < 24; ++p){
    float kv = ker[io*24 + p];
    float2 f = Fc[p*NLM + lm];
    acc.x += kv*f.x; acc.y += kv*f.y;
  }
  acc.x *= (float)SCALING; acc.y *= (float)SCALING;
  ycT[((size_t)(o*16 + i))*NLM + lm] = acc;
}

// ---- pipeline --------------------------------------------------------
// xf[mj][b][zi]; 4-way ILP phase recurrence
__global__ __launch_bounds__(256) void k_dft(const float* x, float2* xf){
  __shared__ float rows[4][128];
  int t = threadIdx.x, g = t >> 6, lane = t & 63;
  int r = blockIdx.x*4 + g;
  int zi = r & 255, b = r >> 8;
  const float* xr = x + ((size_t)zi*128 + b)*128;
  rows[g][lane]    = xr[lane];
  rows[g][lane+64] = xr[lane+64];
  __syncthreads();
  if (lane < NBINS){
    int m = lane - 19;
    float th = -2.0f*(float)PI_D*(float)m/128.0f;
    float sn1, cs1; sincosf(th, &sn1, &cs1);
    float cs2 = cs1*cs1 - sn1*sn1, sn2 = 2.f*cs1*sn1;
    float cs4 = cs2*cs2 - sn2*sn2, sn4 = 2.f*cs2*sn2;
    float w0r = 1.f, w0i = 0.f;
    float w1r = cs1, w1i = sn1;
    float w2r = cs2, w2i = sn2;
    float w3r = cs1*cs2 - sn1*sn2, w3i = cs1*sn2 + sn1*cs2;
    float2 a0 = make_float2(0.f,0.f), a1 = a0, a2 = a0, a3 = a0;
    const float* rw = rows[g];
    #pragma unroll 4
    for (int q = 0; q < 32; ++q){
      float v0 = rw[4*q], v1 = rw[4*q+1], v2 = rw[4*q+2], v3 = rw[4*q+3];
      a0.x += v0*w0r; a0.y += v0*w0i;
      a1.x += v1*w1r; a1.y += v1*w1i;
      a2.x += v2*w2r; a2.y += v2*w2i;
      a3.x += v3*w3r; a3.y += v3*w3i;
      float nr;
      nr = w0r*cs4 - w0i*sn4; w0i = w0r*sn4 + w0i*cs4; w0r = nr;
      nr = w1r*cs4 - w1i*sn4; w1i = w1r*sn4 + w1i*cs4; w1r = nr;
      nr = w2r*cs4 - w2i*sn4; w2i = w2r*sn4 + w2i*cs4; w2r = nr;
      nr = w3r*cs4 - w3i*sn4; w3i = w3r*sn4 + w3i*cs4; w3r = nr;
    }
    float2 acc = make_float2(a0.x+a1.x+a2.x+a3.x, a0.y+a1.y+a2.y+a3.y);
    xf[((size_t)lane*128 + b)*256 + zi] = acc;
  }
}

// partial beta-contraction: xlp[c][lm][zi], c = 32-b chunk (r7 parallel form)
__global__ void k_xlp(const float2* xf, const float* w_s2, float2* xlp){
  int lm = blockIdx.x, c = blockIdx.y, zi = threadIdx.x;
  int l = lidx(lm); int m = lm - l*l - l;
  int bin = m + 19;
  float2 acc = make_float2(0.f, 0.f);
  for (int b = c*32; b < c*32+32; ++b){
    float w = w_s2[b*NLM + lm];
    float2 v = xf[((size_t)bin*128 + b)*256 + zi];
    acc.x += w*v.x; acc.y += w*v.y;
  }
  xlp[((size_t)(c*NLM + lm))*256 + zi] = acc;
}

// sum chunks -> xlT[zi][lm]
__global__ void k_xlsum(const float2* xlp, float2* xlT){
  int lm = blockIdx.x, zi = threadIdx.x;
  float2 s = make_float2(0.f, 0.f);
  for (int c = 0; c < 4; ++c){
    float2 v = xlp[((size_t)(c*NLM + lm))*256 + zi];
    s.x += v.x; s.y += v.y;
  }
  xlT[(size_t)zi*NLM + lm] = s;
}

// zl2 in SORTED layout: z3[zo][k'], k' = lbase(l) + global pair rank
__global__ void k_zl2s(const float2* xlT, const float2* ycT, const int* ridx2,
                       float2* z3){
  int tid = blockIdx.x*256 + threadIdx.x;
  if (tid >= NZO*NPACK) return;
  int zo = tid / NPACK, k = tid % NPACK;
  int info = ridx2[k];
  int mj = info & 255, njs = (info>>8)&255, l = info>>16;
  int z = zo >> 5, o = zo & 31;
  int lmm = l*l + l + mj;
  int lmn = l*l + l + (njs - 19);
  const float2* xrow = xlT + (size_t)(z*16)*NLM;
  const float2* yrow = ycT + (size_t)(o*16)*NLM;
  float2 acc = make_float2(0.f, 0.f);
  #pragma unroll 16
  for (int i = 0; i < 16; ++i){
    float2 a  = xrow[i*NLM + lmm];
    float2 bb = yrow[i*NLM + lmn];
    acc.x += a.x*bb.x - a.y*bb.y;
    acc.y += a.x*bb.y + a.y*bb.x;
  }
  z3[tid] = acc;
}

// ---- stage 1 with z-register reuse: one thread per (zo,s), loop b ----
__global__ __launch_bounds__(256) void k_s1g(const float* dinv3, const float2* z3,
                                             const int* psort, float2* Cg){
  int tid = blockIdx.x*256 + threadIdx.x;
  if (tid >= NZO*NPAIR) return;
  int zo = tid / NPAIR, s = tid % NPAIR;
  int pk = psort[s];
  int mj = pk & 255, njs = (pk>>8)&255;
  int d_ = njs - 19, ad = d_ < 0 ? -d_ : d_;
  int lam = mj > ad ? mj : ad;
  const float2* zrow = z3 + (size_t)zo*NPACK;
  float2 zr[20];
  #pragma unroll
  for (int l = 0; l < 20; ++l){
    float2 v = zrow[lbase(l) + s];
    bool act = (l >= lam);
    zr[l].x = act ? v.x : 0.f;
    zr[l].y = act ? v.y : 0.f;
  }
  for (int b = 0; b < 40; ++b){
    const float* drow = dinv3 + (size_t)b*NPACK;
    float2 c = make_float2(0.f, 0.f);
    #pragma unroll
    for (int l = 0; l < 20; ++l){
      float dv = drow[lbase(l) + s];
      c.x += dv*zr[l].x;
      c.y += dv*zr[l].y;
    }
    Cg[((size_t)(zo*40 + b))*NPAIR + s] = c;   // coalesced, sorted order
  }
}

// ---- synthesis stages 2+3: block = (zo, 2b), 256 threads, VGPR<=64 ---
// (8 waves/EU declared: cap VGPR at 64 so LDS (5 blocks/CU) becomes binder)
__global__ __launch_bounds__(256, 8) void k_s2(const float2* Cg, const int* psort,
                                               const float2* wsyn, const float* bias,
                                               float* out){
  __shared__ float2 Cs[2][NPAIR];     // 12.48 KB
  __shared__ float2 Gs[2][800];       // 12.8 KB
  __shared__ float2 Wq[390];          // [njs][g0<10]  3.12 KB
  __shared__ float2 Wma[200];         // [mj][a0<10]   1.6 KB  -> 30 KB
  int blk = blockIdx.x;               // zo*20 + bg
  int zo = blk / 20, bg = blk % 20;
  int b0 = bg*2;
  int o = zo & 31;
  int t = threadIdx.x;

  const float2* crow = Cg + (size_t)(zo*40 + b0)*NPAIR;
  for (int idx = t; idx < 2*NPAIR; idx += 256){
    int b_ = idx / NPAIR, p = idx % NPAIR;
    int pk = psort[p];
    Cs[b_][(pk&255)*39 + ((pk>>8)&255)] = crow[b_*NPAIR + p];
  }
  for (int idx = t; idx < 390; idx += 256){
    int njs = idx/10, g0 = idx%10;
    Wq[idx] = wsyn[njs*40 + g0];
  }
  for (int idx = t; idx < 200; idx += 256){
    int mj = idx/10, a0 = idx%10;
    Wma[idx] = wsyn[(19+mj)*40 + a0];
  }
  __syncthreads();

  // stage 2: G[mj][g0+10k] = sum_r i^{rk} S_r,  S_r over njs-residue classes
  for (int it = t; it < 400; it += 256){
    int b_ = it / 200, r2 = it % 200;
    int mj = r2 / 10, g0 = r2 % 10;
    const float2* cr = Cs[b_] + mj*39;
    float2 S0 = make_float2(0.f,0.f), S1 = S0, S2 = S0, S3 = S0;
    for (int j = 0; j < 9; ++j){        // r=0: njs = 3+4j
      float2 c = cr[3+4*j]; float2 w = Wq[(3+4*j)*10 + g0];
      S0.x += c.x*w.x - c.y*w.y; S0.y += c.x*w.y + c.y*w.x;
    }
    for (int j = 0; j < 10; ++j){       // r=1: njs = 4j
      float2 c = cr[4*j]; float2 w = Wq[(4*j)*10 + g0];
      S1.x += c.x*w.x - c.y*w.y; S1.y += c.x*w.y + c.y*w.x;
    }
    for (int j = 0; j < 10; ++j){       // r=2: njs = 1+4j
      float2 c = cr[1+4*j]; float2 w = Wq[(1+4*j)*10 + g0];
      S2.x += c.x*w.x - c.y*w.y; S2.y += c.x*w.y + c.y*w.x;
    }
    for (int j = 0; j < 10; ++j){       // r=3: njs = 2+4j
      float2 c = cr[2+4*j]; float2 w = Wq[(2+4*j)*10 + g0];
      S3.x += c.x*w.x - c.y*w.y; S3.y += c.x*w.y + c.y*w.x;
    }
    float2* gb = Gs[b_];
    gb[mj*40 + g0     ] = make_float2(S0.x+S1.x+S2.x+S3.x, S0.y+S1.y+S2.y+S3.y);
    gb[mj*40 + g0 + 10] = make_float2(S0.x-S1.y-S2.x+S3.y, S0.y+S1.x-S2.y-S3.x);
    gb[mj*40 + g0 + 20] = make_float2(S0.x-S1.x+S2.x-S3.x, S0.y-S1.y+S2.y-S3.y);
    gb[mj*40 + g0 + 30] = make_float2(S0.x+S1.y-S2.x-S3.y, S0.y-S1.x-S2.y+S3.x);
  }
  __syncthreads();

  // stage 3: out[a0+10k][g] = G0[g].x + 2 Re(sum_r i^{rk} S_r) + bias
  float bv = bias[o];
  for (int idx = t; idx < 800; idx += 256){
    int b_ = idx / 400, r3 = idx % 400;
    int a0 = r3 / 40, g = r3 % 40;
    const float2* gb = Gs[b_];
    float S0x = 0.f, S2x = 0.f;
    float2 S1 = make_float2(0.f,0.f), S3 = S1;
    for (int j = 0; j < 4; ++j){        // r=0: mj = 4+4j
      float2 gv = gb[(4+4*j)*40 + g]; float2 w = Wma[(4+4*j)*10 + a0];
      S0x += gv.x*w.x - gv.y*w.y;
    }
    for (int j = 0; j < 5; ++j){        // r=1: mj = 1+4j
      float2 gv = gb[(1+4*j)*40 + g]; float2 w = Wma[(1+4*j)*10 + a0];
      S1.x += gv.x*w.x - gv.y*w.y; S1.y += gv.x*w.y + gv.y*w.x;
    }
    for (int j = 0; j < 5; ++j){        // r=2: mj = 2+4j
      float2 gv = gb[(2+4*j)*40 + g]; float2 w = Wma[(2+4*j)*10 + a0];
      S2x += gv.x*w.x - gv.y*w.y;
    }
    for (int j = 0; j < 5; ++j){        // r=3: mj = 3+4j
      float2 gv = gb[(3+4*j)*40 + g]; float2 w = Wma[(3+4*j)*10 + a0];
      S3.x += gv.x*w.x - gv.y*w.y; S3.y += gv.x*w.y + gv.y*w.x;
    }
    float g0v = gb[g].x;
    float* orow = out + ((size_t)zo*40 + b0 + b_)*1600;
    orow[(a0     )*40 + g] = g0v + 2.f*(S0x + S1.x + S2x + S3.x) + bv;
    orow[(a0 + 10)*40 + g] = g0v + 2.f*(S0x - S1.y - S2x + S3.y) + bv;
    orow[(a0 + 20)*40 + g] = g0v + 2.f*(S0x - S1.x + S2x - S3.x) + bv;
    orow[(a0 + 30)*40 + g] = g0v + 2.f*(S0x + S1.y - S2x - S3.y) + bv;
  }
}

extern "C" void kernel_launch(void* const* d_in, const int* in_sizes, int n_in,
                              void* d_out, int out_size, void* d_ws, size_t ws_size,
                              hipStream_t stream) {
  const float* x    = (const float*)d_in[0];
  const float* ker  = (const float*)d_in[1];
  const float* bias = (const float*)d_in[2];
  float* out = (float*)d_out;

  char* ws = (char*)d_ws;
  size_t cur = 0;
  auto alloc = [&](size_t bytes)->char*{
    char* p = ws + cur;
    cur += (bytes + 255) & ~(size_t)255;
    return p;
  };
  double* lg    = (double*)alloc(64*8);
  double* wq    = (double*)alloc(128*8);
  int*    psort = (int*)   alloc(NPAIR*4);
  int*    ridx2 = (int*)   alloc(NPACK*4);
  float2* wsyn  = (float2*)alloc((size_t)1560*8);
  float*  w_s2  = (float*) alloc((size_t)NB_IN*NLM*4);
  float*  dinv3 = (float*) alloc((size_t)TWOB*NPACK*4);
  float2* Fc    = (float2*)alloc((size_t)24*NLM*8);
  float2* ycT   = (float2*)alloc((size_t)512*400*8);
  float2* xf    = (float2*)alloc((size_t)NBINS*128*256*8);
  float2* xlp   = (float2*)alloc((size_t)4*NLM*256*8);
  float2* xlT   = (float2*)alloc((size_t)256*NLM*8);
  float2* z3    = (float2*)alloc((size_t)NZO*NPACK*8);      // 45 MB
  float2* Cg    = (float2*)alloc((size_t)NZO*40*NPAIR*8);   // 128 MB
  (void)ws_size; (void)in_sizes; (void)n_in; (void)out_size;

  k_init  <<<1, 256, 0, stream>>>(lg, wq, psort, ridx2, wsyn);
  k_tables<<<671, 256, 0, stream>>>(w_s2, dinv3, Fc, ridx2, lg, wq);
  k_yc    <<<800, 256, 0, stream>>>(ker, Fc, ycT);

  k_dft  <<<(256*128)/4, 256, 0, stream>>>(x, xf);
  k_xlp  <<<dim3(NLM, 4), 256, 0, stream>>>(xf, w_s2, xlp);
  k_xlsum<<<NLM, 256, 0, stream>>>(xlp, xlT);
  k_zl2s <<<(NZO*NPACK + 255)/256, 256, 0, stream>>>(xlT, ycT, ridx2, z3);
  k_s1g  <<<(NZO*NPAIR + 255)/256, 256, 0, stream>>>(dinv3, z3, psort, Cg);
  k_s2   <<<NZO*20, 256, 0, stream>>>(Cg, psort, wsyn, bias, out);
}